// Round 2
// baseline (450.172 us; speedup 1.0000x reference)
//
#include <hip/hip_runtime.h>

#define DIM 4096
#define NUM_SHARDS 8
#define TOTAL_ELEMS (4 * 4096 * 4096)   // BATCH * SEQ * DIM
#define TOTAL_F4 (TOTAL_ELEMS / 4)      // 16,777,216 float4 elements
#define DIM_F4 (DIM / 4)                // 1024 float4 per row
#define BLOCK 256
#define GRID_BLOCKS 2048                // 2048*256 = 524288 threads = 512 * DIM_F4
                                        // -> column index (i & 1023) is loop-invariant

// Native clang vector type: __builtin_nontemporal_* accepts this (it rejects
// the HIP_vector_type<float,4> wrapper class).
typedef float f4 __attribute__((ext_vector_type(4)));

// Single fused kernel: no workspace, no build_w pass.
// Each thread resolves its 4 per-dim weights ONCE via the shard gather
// (shard_map: 16 KiB, shards: 128 KiB -> L2-resident, amortized over 32
// grid-stride iterations), then streams x -> out at HBM rate with the
// weights held in registers. Non-temporal hints keep the streaming
// traffic from evicting the weight tables.
__global__ __launch_bounds__(BLOCK) void fused_scale_kernel(
    const f4* __restrict__ x,
    const float* __restrict__ shards,
    const int* __restrict__ shard_map,
    f4* __restrict__ out) {
    const int tid = blockIdx.x * BLOCK + threadIdx.x;

    // Column within the DIM axis; invariant across grid-stride iterations
    // because stride (524288) is a multiple of DIM_F4 (1024).
    const int c = tid & (DIM_F4 - 1);
    const int d = c << 2;

    f4 wv;
    wv.x = shards[shard_map[d + 0] * DIM + (d + 0)];
    wv.y = shards[shard_map[d + 1] * DIM + (d + 1)];
    wv.z = shards[shard_map[d + 2] * DIM + (d + 2)];
    wv.w = shards[shard_map[d + 3] * DIM + (d + 3)];

    const int stride = GRID_BLOCKS * BLOCK;   // 524288
    #pragma unroll 4
    for (int i = tid; i < TOTAL_F4; i += stride) {
        f4 xv = __builtin_nontemporal_load(&x[i]);
        f4 ov = xv * wv;
        __builtin_nontemporal_store(ov, &out[i]);
    }
}

extern "C" void kernel_launch(void* const* d_in, const int* in_sizes, int n_in,
                              void* d_out, int out_size, void* d_ws, size_t ws_size,
                              hipStream_t stream) {
    const float* x = (const float*)d_in[0];
    const float* shards = (const float*)d_in[1];
    const int* shard_map = (const int*)d_in[2];   // JAX default x64-off: int32
    float* out = (float*)d_out;

    // d_ws intentionally unused: workspace use costs a 1-GiB re-poison fill
    // (~165 us) per timed iteration.
    (void)d_ws; (void)ws_size;

    fused_scale_kernel<<<GRID_BLOCKS, BLOCK, 0, stream>>>(
        (const f4*)x, shards, shard_map, (f4*)out);
}

// Round 3
// 435.821 us; speedup vs baseline: 1.0329x; 1.0329x over previous
//
#include <hip/hip_runtime.h>

#define DIM 4096
#define NUM_SHARDS 8
#define TOTAL_ELEMS (4 * 4096 * 4096)   // BATCH * SEQ * DIM
#define TOTAL_F4 (TOTAL_ELEMS / 4)      // 16,777,216 float4 elements
#define HALF_F4 (TOTAL_F4 / 2)          // 8,388,608 — multiple of DIM_F4
#define DIM_F4 (DIM / 4)                // 1024 float4 per row

// Kernel 1: collapse the shard gather into a flat per-dim weight vector.
// w[d] = shards[shard_map[d] * DIM + d]. 16 KiB into d_ws.
// (d_ws use is free: the 1-GiB re-poison fills run unconditionally —
// verified round 2, fills present with ws untouched.)
__global__ void build_w_kernel(const float* __restrict__ shards,
                               const int* __restrict__ shard_map,
                               float* __restrict__ w) {
    int d = blockIdx.x * blockDim.x + threadIdx.x;
    if (d < DIM) {
        w[d] = shards[shard_map[d] * DIM + d];
    }
}

// Kernel 2: pure-bandwidth elementwise multiply, float4-vectorized,
// flat indexing (near-sequential sweep — grid-stride/NT variant measured
// 30 us slower, round 2). Each thread handles elements i and i+HALF_F4:
// HALF_F4 is a multiple of DIM_F4, so both share the same column and one
// w-table read (L1-resident 16 KiB) serves both.
__global__ __launch_bounds__(256) void scale_kernel(const float4* __restrict__ x,
                                                    const float4* __restrict__ w,
                                                    float4* __restrict__ out) {
    int i = blockIdx.x * 256 + threadIdx.x;      // 0 .. HALF_F4-1
    float4 wv = w[i & (DIM_F4 - 1)];
    float4 a = x[i];
    float4 b = x[i + HALF_F4];
    float4 oa, ob;
    oa.x = a.x * wv.x;  oa.y = a.y * wv.y;  oa.z = a.z * wv.z;  oa.w = a.w * wv.w;
    ob.x = b.x * wv.x;  ob.y = b.y * wv.y;  ob.z = b.z * wv.z;  ob.w = b.w * wv.w;
    out[i] = oa;
    out[i + HALF_F4] = ob;
}

extern "C" void kernel_launch(void* const* d_in, const int* in_sizes, int n_in,
                              void* d_out, int out_size, void* d_ws, size_t ws_size,
                              hipStream_t stream) {
    const float* x = (const float*)d_in[0];
    const float* shards = (const float*)d_in[1];
    const int* shard_map = (const int*)d_in[2];
    float* w = (float*)d_ws;   // 16 KiB scratch
    float* out = (float*)d_out;

    build_w_kernel<<<DIM / 256, 256, 0, stream>>>(shards, shard_map, w);

    scale_kernel<<<HALF_F4 / 256, 256, 0, stream>>>(
        (const float4*)x, (const float4*)w, (float4*)out);
}

// Round 4
// 420.082 us; speedup vs baseline: 1.0716x; 1.0375x over previous
//
#include <hip/hip_runtime.h>
#include <hip/hip_bf16.h>

#define DIM 4096
#define NUM_SHARDS 8
#define TOTAL_ELEMS (4 * 4096 * 4096)   // BATCH * SEQ * DIM
#define TOTAL_F4 (TOTAL_ELEMS / 4)      // 16,777,216 float4 elements
#define DIM_F4 (DIM / 4)                // 1024 float4 per row

// Kernel 1: collapse the shard gather into a flat per-dim weight vector.
// w[d] = shards[shard_map[d] * DIM + d]. 16 KiB output into d_ws.
// (d_ws use is free: the 1-GiB re-poison fills run unconditionally —
// verified round 2, fills present with ws untouched.)
__global__ void build_w_kernel(const float* __restrict__ shards,
                               const int* __restrict__ shard_map,
                               float* __restrict__ w) {
    int d = blockIdx.x * blockDim.x + threadIdx.x;
    if (d < DIM) {
        w[d] = shards[shard_map[d] * DIM + d];
    }
}

// Kernel 2: pure bandwidth elementwise multiply, float4-vectorized, flat
// indexing — one contiguous address front per wave. Measured-best structure:
// grid-stride+NT variant +30us (round 2), far-split dual-stream +15us
// (round 3). i & 1023 maps a flat float4 index to its DIM-axis position
// (DIM/4 = 1024, power of two). w table (16 KiB) stays L1-resident.
__global__ __launch_bounds__(256) void scale_kernel(const float4* __restrict__ x,
                                                    const float4* __restrict__ w,
                                                    float4* __restrict__ out) {
    int i = blockIdx.x * 256 + threadIdx.x;
    float4 xv = x[i];
    float4 wv = w[i & (DIM_F4 - 1)];
    float4 ov;
    ov.x = xv.x * wv.x;
    ov.y = xv.y * wv.y;
    ov.z = xv.z * wv.z;
    ov.w = xv.w * wv.w;
    out[i] = ov;
}

extern "C" void kernel_launch(void* const* d_in, const int* in_sizes, int n_in,
                              void* d_out, int out_size, void* d_ws, size_t ws_size,
                              hipStream_t stream) {
    const float* x = (const float*)d_in[0];
    const float* shards = (const float*)d_in[1];
    const int* shard_map = (const int*)d_in[2];
    float* w = (float*)d_ws;   // 16 KiB scratch; rebuilt every call
    float* out = (float*)d_out;

    build_w_kernel<<<DIM / 256, 256, 0, stream>>>(shards, shard_map, w);

    scale_kernel<<<TOTAL_F4 / 256, 256, 0, stream>>>(
        (const float4*)x, (const float4*)w, (float4*)out);
}